// Round 6
// baseline (837.671 us; speedup 1.0000x reference)
//
#include <hip/hip_runtime.h>

// AttnHGCN.forward_ui — 3-layer bipartite LightGCN-style propagation.
// R6: MLP push. R4/R5 evidence: scatter is LATENCY-bound (1.86 TB/s = 29% of
// HBM ceiling; all gains tracked outstanding-request count, WRITE_SIZE never
// moved -> L2 won't coalesce partial-line random stores regardless of
// locality). So: (a) scatter 8 edges/thread = 16 atomic+store pairs in
// flight; (b) gather restructured to 8 slots x 8 lanes x 2xfloat4 = 16
// outstanding row-gather loads per wave, half the loop trips (avg deg 27).

constexpr int N_USERS = 100000;
constexpr int N_ITEMS = 50000;
constexpr int CH      = 64;
constexpr int N_EDGES = 2000000;
constexpr int LAYERS  = 3;
constexpr int NROWS   = N_USERS + N_ITEMS;          // 150000 combined dest rows
constexpr int NDIR    = 2 * N_EDGES;                // 4M directed edges

constexpr int PASSES  = 8;
constexpr int WROWS   = NROWS / PASSES;             // 18750 rows per window
constexpr int QEDGES  = N_EDGES / 4;                // 500000 int4 edge-quads
constexpr int OEDGES  = N_EDGES / 8;                // 250000 8-edge groups
constexpr int BPP8    = (OEDGES + 255) / 256;       // blocks per pass = 977

constexpr long long ITEM_ELEMS = (long long)N_ITEMS * CH;  // 3,200,000
constexpr long long USER_ELEMS = (long long)N_USERS * CH;  // 6,400,000
constexpr long long TOT_ELEMS  = ITEM_ELEMS + USER_ELEMS;  // 9,600,000

// ---------------- CSR build ----------------

__global__ __launch_bounds__(256) void hist_kernel(
    const int4* __restrict__ u4, const int4* __restrict__ i4,
    int* __restrict__ counts) {
  int q = blockIdx.x * 256 + threadIdx.x;
  if (q >= QEDGES) return;
  int4 u = u4[q];
  int4 it = i4[q];
  atomicAdd(&counts[u.x], 1);
  atomicAdd(&counts[u.y], 1);
  atomicAdd(&counts[u.z], 1);
  atomicAdd(&counts[u.w], 1);
  atomicAdd(&counts[N_USERS + it.x], 1);
  atomicAdd(&counts[N_USERS + it.y], 1);
  atomicAdd(&counts[N_USERS + it.z], 1);
  atomicAdd(&counts[N_USERS + it.w], 1);
}

// per-256-block exclusive scan; block sums out
__global__ __launch_bounds__(256) void scanA_kernel(
    const int* __restrict__ counts, int* __restrict__ row_ptr,
    int* __restrict__ blksums, int n) {
  __shared__ int sh[256];
  int t = threadIdx.x;
  int i = blockIdx.x * 256 + t;
  int v = (i < n) ? counts[i] : 0;
  int x = v;
  sh[t] = x; __syncthreads();
  for (int d = 1; d < 256; d <<= 1) {
    int add = (t >= d) ? sh[t - d] : 0;
    __syncthreads();
    x += add; sh[t] = x;
    __syncthreads();
  }
  if (i < n) row_ptr[i] = x - v;  // exclusive within block
  if (t == 255) blksums[blockIdx.x] = x;
}

// single-block exclusive scan of block sums (n2 <= 1024)
__global__ __launch_bounds__(1024) void scanB_kernel(int* __restrict__ blksums, int n2) {
  __shared__ int sh[1024];
  int t = threadIdx.x;
  int v = (t < n2) ? blksums[t] : 0;
  int x = v;
  sh[t] = x; __syncthreads();
  for (int d = 1; d < 1024; d <<= 1) {
    int add = (t >= d) ? sh[t - d] : 0;
    __syncthreads();
    x += add; sh[t] = x;
    __syncthreads();
  }
  if (t < n2) blksums[t] = x - v;  // exclusive
}

// add block offsets; init cursor; set terminator
__global__ __launch_bounds__(256) void scanC_kernel(
    int* __restrict__ row_ptr, const int* __restrict__ blksums,
    int* __restrict__ cursor, int n) {
  int i = blockIdx.x * 256 + threadIdx.x;
  if (i < n) {
    int p = row_ptr[i] + blksums[i >> 8];
    row_ptr[i] = p;
    cursor[i] = p;
  }
  if (i == 0) row_ptr[n] = NDIR;
}

// XCD-pinned windowed scatter, 8 edges/thread: 16 independent atomic+store
// pairs in flight per thread (latency-bound kernel; MLP is the lever).
__global__ __launch_bounds__(256) void scatter_csr_win(
    const int4* __restrict__ u4, const int4* __restrict__ i4,
    const float4* __restrict__ w4, int* __restrict__ cursor,
    int2* __restrict__ csr) {
  int pass = blockIdx.x % PASSES;
  int q = (blockIdx.x / PASSES) * 256 + threadIdx.x;
  if (q >= OEDGES) return;
  const int wlo = pass * WROWS;

  int4   ua = u4[2 * q],     ub = u4[2 * q + 1];
  int4   ia = i4[2 * q],     ib = i4[2 * q + 1];
  float4 wa = w4[2 * q],     wb = w4[2 * q + 1];

#define PROC(UU, II, WW)                                             \
  {                                                                  \
    int ru = (UU), ri = N_USERS + (II);                              \
    int wb_ = __float_as_int(WW);                                    \
    if ((unsigned)(ru - wlo) < (unsigned)WROWS) {                    \
      int p = atomicAdd(&cursor[ru], 1);                             \
      csr[p] = make_int2((II), wb_);                                 \
    }                                                                \
    if ((unsigned)(ri - wlo) < (unsigned)WROWS) {                    \
      int p = atomicAdd(&cursor[ri], 1);                             \
      csr[p] = make_int2((UU), wb_);                                 \
    }                                                                \
  }
  PROC(ua.x, ia.x, wa.x)
  PROC(ua.y, ia.y, wa.y)
  PROC(ua.z, ia.z, wa.z)
  PROC(ua.w, ia.w, wa.w)
  PROC(ub.x, ib.x, wb.x)
  PROC(ub.y, ib.y, wb.y)
  PROC(ub.z, ib.z, wb.z)
  PROC(ub.w, ib.w, wb.w)
#undef PROC
}

// ---------------- per-layer fused gather ----------------
// One wave per destination row; lane = slot(3b) x chan8(3b). Each slot-lane
// group of 8 lanes covers one edge; each lane holds channels [c8, c8+8) via
// two independent float4 loads -> 8 edges x 2 loads = 16 outstanding loads
// per wave. Butterfly-reduce the 8 slots. Epilogue fuses residual:
//   MODE 0 (layer 1):   dst = acc;  out = emb + acc
//   MODE 1 (mid layer): dst = acc;  out += acc
//   MODE 2 (last):                  out = (out + acc) * 1/(LAYERS+1)
template <int MODE>
__global__ __launch_bounds__(256) void gather_fused(
    const float* __restrict__ it_tab,  // gather-source item table
    const float* __restrict__ u_tab,   // gather-source user table
    float* __restrict__ dst,           // [it|u] layer output (MODE<2)
    float* __restrict__ out,           // [item_acc | user_acc]
    const int2* __restrict__ csr,
    const int* __restrict__ row_ptr) {
  int row = blockIdx.x * 4 + (threadIdx.x >> 6);
  if (row >= NROWS) return;
  int lane = threadIdx.x & 63;
  int slot = lane >> 3;          // 0..7
  int c8   = (lane & 7) * 8;     // channel offset 0..56

  const float* gtab;             // opposite-side table to gather from
  const float* erow = nullptr;   // dest-side input-emb row (MODE 0)
  float* drow = nullptr;
  float* orow;
  if (row < N_USERS) {
    gtab = it_tab;
    orow = out + ITEM_ELEMS + (long long)row * CH;
    if (MODE < 2)  drow = dst + ITEM_ELEMS + (long long)row * CH;
    if (MODE == 0) erow = u_tab + (long long)row * CH;  // u_tab==user_emb here
  } else {
    int r = row - N_USERS;
    gtab = u_tab;
    orow = out + (long long)r * CH;
    if (MODE < 2)  drow = dst + (long long)r * CH;
    if (MODE == 0) erow = it_tab + (long long)r * CH;   // it_tab==item_emb here
  }

  int beg = row_ptr[row], end = row_ptr[row + 1];
  float4 a0 = make_float4(0.f, 0.f, 0.f, 0.f);
  float4 a1 = make_float4(0.f, 0.f, 0.f, 0.f);
  for (int j = beg + slot; j < end; j += 8) {
    int2  e  = csr[j];
    float we = __int_as_float(e.y);
    const float* p = gtab + (long long)e.x * CH + c8;
    float4 v0 = *(const float4*)p;
    float4 v1 = *(const float4*)(p + 4);
    a0.x += we * v0.x; a0.y += we * v0.y;
    a0.z += we * v0.z; a0.w += we * v0.w;
    a1.x += we * v1.x; a1.y += we * v1.y;
    a1.z += we * v1.z; a1.w += we * v1.w;
  }
  for (int off = 8; off < 64; off <<= 1) {
    a0.x += __shfl_xor(a0.x, off, 64);
    a0.y += __shfl_xor(a0.y, off, 64);
    a0.z += __shfl_xor(a0.z, off, 64);
    a0.w += __shfl_xor(a0.w, off, 64);
    a1.x += __shfl_xor(a1.x, off, 64);
    a1.y += __shfl_xor(a1.y, off, 64);
    a1.z += __shfl_xor(a1.z, off, 64);
    a1.w += __shfl_xor(a1.w, off, 64);
  }
  if (slot == 0) {
    if (MODE == 0) {
      float4 e0 = *(const float4*)(erow + c8);
      float4 e1 = *(const float4*)(erow + c8 + 4);
      *(float4*)(drow + c8)     = a0;
      *(float4*)(drow + c8 + 4) = a1;
      e0.x += a0.x; e0.y += a0.y; e0.z += a0.z; e0.w += a0.w;
      e1.x += a1.x; e1.y += a1.y; e1.z += a1.z; e1.w += a1.w;
      *(float4*)(orow + c8)     = e0;
      *(float4*)(orow + c8 + 4) = e1;
    } else if (MODE == 1) {
      float4 o0 = *(const float4*)(orow + c8);
      float4 o1 = *(const float4*)(orow + c8 + 4);
      *(float4*)(drow + c8)     = a0;
      *(float4*)(drow + c8 + 4) = a1;
      o0.x += a0.x; o0.y += a0.y; o0.z += a0.z; o0.w += a0.w;
      o1.x += a1.x; o1.y += a1.y; o1.z += a1.z; o1.w += a1.w;
      *(float4*)(orow + c8)     = o0;
      *(float4*)(orow + c8 + 4) = o1;
    } else {
      const float s = 1.0f / (LAYERS + 1);
      float4 o0 = *(const float4*)(orow + c8);
      float4 o1 = *(const float4*)(orow + c8 + 4);
      o0.x = (o0.x + a0.x) * s; o0.y = (o0.y + a0.y) * s;
      o0.z = (o0.z + a0.z) * s; o0.w = (o0.w + a0.w) * s;
      o1.x = (o1.x + a1.x) * s; o1.y = (o1.y + a1.y) * s;
      o1.z = (o1.z + a1.z) * s; o1.w = (o1.w + a1.w) * s;
      *(float4*)(orow + c8)     = o0;
      *(float4*)(orow + c8 + 4) = o1;
    }
  }
}

// ---------------- fallback (R1 atomic path) ----------------

__global__ __launch_bounds__(256) void atomic_scatter_kernel(
    const float* __restrict__ src, float* __restrict__ dst,
    const int* __restrict__ u_idx, const int* __restrict__ i_idx,
    const float* __restrict__ w) {
  long long tid = (long long)blockIdx.x * blockDim.x + threadIdx.x;
  int edge = (int)(tid >> 4);
  if (edge >= N_EDGES) return;
  int c = ((int)tid & 15) * 4;
  int ui = u_idx[edge], ii = i_idx[edge];
  float we = w[edge];
  float4 itv = *(const float4*)(src + (long long)ii * CH + c);
  float4 uv  = *(const float4*)(src + ITEM_ELEMS + (long long)ui * CH + c);
  float* ud = dst + ITEM_ELEMS + (long long)ui * CH + c;
  float* id = dst + (long long)ii * CH + c;
  unsafeAtomicAdd(ud + 0, we * itv.x);
  unsafeAtomicAdd(ud + 1, we * itv.y);
  unsafeAtomicAdd(ud + 2, we * itv.z);
  unsafeAtomicAdd(ud + 3, we * itv.w);
  unsafeAtomicAdd(id + 0, we * uv.x);
  unsafeAtomicAdd(id + 1, we * uv.y);
  unsafeAtomicAdd(id + 2, we * uv.z);
  unsafeAtomicAdd(id + 3, we * uv.w);
}

__global__ __launch_bounds__(256) void add_scale_kernel(
    float* __restrict__ acc, const float* __restrict__ add, float s, long long n4) {
  long long i = (long long)blockIdx.x * blockDim.x + threadIdx.x;
  if (i >= n4) return;
  float4 a = ((const float4*)acc)[i];
  float4 b = ((const float4*)add)[i];
  a.x = (a.x + b.x) * s;
  a.y = (a.y + b.y) * s;
  a.z = (a.z + b.z) * s;
  a.w = (a.w + b.w) * s;
  ((float4*)acc)[i] = a;
}

extern "C" void kernel_launch(void* const* d_in, const int* in_sizes, int n_in,
                              void* d_out, int out_size, void* d_ws, size_t ws_size,
                              hipStream_t stream) {
  const float* user_emb = (const float*)d_in[1];
  const float* item_emb = (const float*)d_in[2];
  const int*   edges    = (const int*)d_in[3];
  const int*   u_idx    = edges;            // row 0
  const int*   i_idx    = edges + N_EDGES;  // row 1
  const float* w        = (const float*)d_in[4];

  float* out = (float*)d_out;  // [item_acc | user_acc]

  // workspace layout (4B units)
  float* buf_a   = (float*)d_ws;                 // TOT_ELEMS
  float* buf_b   = buf_a + TOT_ELEMS;            // TOT_ELEMS
  int2*  csr     = (int2*)(buf_b + TOT_ELEMS);   // NDIR int2
  int*   counts  = (int*)(csr + NDIR);           // NROWS
  int*   row_ptr = counts + NROWS;               // NROWS + 1
  int*   cursor  = row_ptr + NROWS + 1;          // NROWS
  int*   blksums = cursor + NROWS;               // 1024
  const size_t needed =
      ((size_t)2 * TOT_ELEMS + 2 * (size_t)NDIR + 3 * (size_t)NROWS + 1 + 1024) * 4;

  if (ws_size >= needed) {
    // ---- CSR build (once per call) ----
    hipMemsetAsync(counts, 0, (size_t)NROWS * sizeof(int), stream);
    const int qblocks = (QEDGES + 255) / 256;  // 1954
    hist_kernel<<<qblocks, 256, 0, stream>>>(
        (const int4*)u_idx, (const int4*)i_idx, counts);
    const int nblocksA = (NROWS + 255) / 256;  // 587 <= 1024
    scanA_kernel<<<nblocksA, 256, 0, stream>>>(counts, row_ptr, blksums, NROWS);
    scanB_kernel<<<1, 1024, 0, stream>>>(blksums, nblocksA);
    scanC_kernel<<<nblocksA, 256, 0, stream>>>(row_ptr, blksums, cursor, NROWS);
    scatter_csr_win<<<PASSES * BPP8, 256, 0, stream>>>(
        (const int4*)u_idx, (const int4*)i_idx, (const float4*)w, cursor, csr);

    // ---- layers (gather + fused residual) ----
    const int gather_blocks = (NROWS + 3) / 4;  // 4 rows (waves) per block
    // L1: gather from input tables; out = emb + l1; buf_a = l1
    gather_fused<0><<<gather_blocks, 256, 0, stream>>>(
        item_emb, user_emb, buf_a, out, csr, row_ptr);
    // L2: gather from buf_a; out += l2; buf_b = l2
    gather_fused<1><<<gather_blocks, 256, 0, stream>>>(
        buf_a, buf_a + ITEM_ELEMS, buf_b, out, csr, row_ptr);
    // L3: gather from buf_b; out = (out + l3) * 0.25
    gather_fused<2><<<gather_blocks, 256, 0, stream>>>(
        buf_b, buf_b + ITEM_ELEMS, nullptr, out, csr, row_ptr);
  } else {
    // ---- fallback: R1 atomic scatter ----
    const size_t item_bytes = (size_t)ITEM_ELEMS * sizeof(float);
    const size_t user_bytes = (size_t)USER_ELEMS * sizeof(float);
    hipMemcpyAsync(buf_a,              item_emb, item_bytes, hipMemcpyDeviceToDevice, stream);
    hipMemcpyAsync(buf_a + ITEM_ELEMS, user_emb, user_bytes, hipMemcpyDeviceToDevice, stream);
    hipMemcpyAsync(out,                item_emb, item_bytes, hipMemcpyDeviceToDevice, stream);
    hipMemcpyAsync(out + ITEM_ELEMS,   user_emb, user_bytes, hipMemcpyDeviceToDevice, stream);
    const long long st = (long long)N_EDGES * 16;
    const int sb = (int)((st + 255) / 256);
    const long long n4 = TOT_ELEMS / 4;
    const int add_blocks = (int)((n4 + 255) / 256);
    float* src = buf_a;
    float* dst = buf_b;
    for (int l = 0; l < LAYERS; ++l) {
      hipMemsetAsync(dst, 0, (size_t)TOT_ELEMS * sizeof(float), stream);
      atomic_scatter_kernel<<<sb, 256, 0, stream>>>(src, dst, u_idx, i_idx, w);
      const float s = (l == LAYERS - 1) ? (1.0f / (LAYERS + 1)) : 1.0f;
      add_scale_kernel<<<add_blocks, 256, 0, stream>>>(out, dst, s, n4);
      float* t = src; src = dst; dst = t;
    }
  }
}